// Round 2
// baseline (401.343 us; speedup 1.0000x reference)
//
#include <hip/hip_runtime.h>
#include <math.h>

// 2D 16-NN distances, N=16384. Brute force O(N^2) with per-thread sorted
// top-17 (self included at d2=0, dropped at the end == reference's idx[:,1:]).
// Block = 256 threads = 64 queries x 4 candidate partitions; candidates staged
// in LDS tiles of 4096 (interleaved j = 4k+part -> broadcast LDS reads).

#define NK    16
#define KP1   17      // top-17 incl. self
#define PARTS 4
#define BQ    64      // queries per block
#define TS    4096    // candidates per LDS tile
#define BLOCK 256

__global__ __launch_bounds__(BLOCK) void knn_kernel(const float* __restrict__ p,
                                                    float* __restrict__ out, int n) {
    __shared__ float2 tile[TS];
    __shared__ float  mrg[BQ][PARTS][KP1];

    const int t    = threadIdx.x;
    const int ql   = t >> 2;     // local query 0..63
    const int part = t & 3;      // candidate partition 0..3
    const int q    = blockIdx.x * BQ + ql;

    float qx = 0.f, qy = 0.f;
    if (q < n) { qx = p[3 * q]; qy = p[3 * q + 1]; }

    float b[KP1];
#pragma unroll
    for (int i = 0; i < KP1; ++i) b[i] = 3.0e38f;

    for (int base = 0; base < n; base += TS) {
        __syncthreads();   // protect previous tile from overwrite
        for (int i = t; i < TS; i += BLOCK) {
            int j = base + i;
            float2 v;
            if (j < n) { v.x = p[3 * j]; v.y = p[3 * j + 1]; }
            else       { v.x = 1.0e18f;  v.y = 1.0e18f; }    // pad: huge finite d2, never survives
            tile[i] = v;
        }
        __syncthreads();

#pragma unroll 4
        for (int k = 0; k < (TS / PARTS); ++k) {
            float2 c = tile[(k << 2) + part];
            float dx = qx - c.x;
            float dy = qy - c.y;
            float d2 = fmaf(dx, dx, dy * dy);
            if (d2 < b[KP1 - 1]) {
                // sorted-insert via med3 clamp: b[s] = clamp(d2, b[s-1], b[s])
#pragma unroll
                for (int s = KP1 - 1; s >= 1; --s)
                    b[s] = __builtin_amdgcn_fmed3f(d2, b[s - 1], b[s]);
                b[0] = fminf(b[0], d2);
            }
        }
    }

#pragma unroll
    for (int i = 0; i < KP1; ++i) mrg[ql][part][i] = b[i];
    __syncthreads();

    if (part == 0 && q < n) {
        // merge the other 3 partitions' sorted lists into b
        for (int pp = 1; pp < PARTS; ++pp) {
#pragma unroll 1
            for (int i = 0; i < KP1; ++i) {
                float d2 = mrg[ql][pp][i];
                if (d2 >= b[KP1 - 1]) break;   // lists ascending; rest can't qualify
#pragma unroll
                for (int s = KP1 - 1; s >= 1; --s)
                    b[s] = __builtin_amdgcn_fmed3f(d2, b[s - 1], b[s]);
                b[0] = fminf(b[0], d2);
            }
        }
        // b[0] == 0 (self); output b[1..16] as distances
        float4* out4 = (float4*)(out + (size_t)q * NK);
#pragma unroll
        for (int i = 0; i < 4; ++i) {
            out4[i] = make_float4(sqrtf(b[4 * i + 1]), sqrtf(b[4 * i + 2]),
                                  sqrtf(b[4 * i + 3]), sqrtf(b[4 * i + 4]));
        }
    }
}

extern "C" void kernel_launch(void* const* d_in, const int* in_sizes, int n_in,
                              void* d_out, int out_size, void* d_ws, size_t ws_size,
                              hipStream_t stream) {
    const float* p = (const float*)d_in[0];
    float* out = (float*)d_out;
    const int n = in_sizes[0] / 3;
    const int grid = (n + BQ - 1) / BQ;
    hipLaunchKernelGGL(knn_kernel, dim3(grid), dim3(BLOCK), 0, stream, p, out, n);
}

// Round 4
// 257.270 us; speedup vs baseline: 1.5600x; 1.5600x over previous
//
#include <hip/hip_runtime.h>
#include <math.h>

// 2D 16-NN distances, N=16384. Brute force O(N^2), per-thread sorted top-17
// (self included at d2=0, dropped at output == reference's idx[:,1:]).
// Round 2: occupancy fix. Block = 256 = 16 queries x 16 candidate partitions;
// grid = N/16 = 1024 blocks -> 4 blocks/CU, 16 waves/CU (~50% occ) vs 11.75%.
// LDS: 2048-pt tile (16KB) + merge scratch (17.4KB) = 33.4KB -> 4 blocks/CU.

#define NK    16
#define KP1   17      // top-17 incl. self
#define PARTS 16
#define BQ    16      // queries per block
#define TS    2048    // candidates per LDS tile
#define BLOCK 256

__global__ __launch_bounds__(BLOCK, 4) void knn_kernel(const float* __restrict__ p,
                                                       float* __restrict__ out, int n) {
    __shared__ float2 tile[TS];
    __shared__ float  mrg[BQ][PARTS][KP1];

    const int t    = threadIdx.x;
    const int ql   = t >> 4;     // local query 0..15
    const int part = t & 15;     // candidate partition 0..15
    const int q    = blockIdx.x * BQ + ql;

    float qx = 0.f, qy = 0.f;
    if (q < n) { qx = p[3 * q]; qy = p[3 * q + 1]; }

    float b[KP1];
#pragma unroll
    for (int i = 0; i < KP1; ++i) b[i] = 3.0e38f;

    for (int base = 0; base < n; base += TS) {
        __syncthreads();   // protect previous tile from overwrite
        for (int i = t; i < TS; i += BLOCK) {
            int j = base + i;
            float2 v;
            if (j < n) { v.x = p[3 * j]; v.y = p[3 * j + 1]; }
            else       { v.x = 1.0e18f;  v.y = 1.0e18f; }    // pad: huge finite d2, never survives
            tile[i] = v;
        }
        __syncthreads();

        // lane reads tile[16k+part]: 16 distinct b64 addrs x 4-way broadcast
        // -> all 32 banks exactly once, conflict-free.
#pragma unroll 4
        for (int k = 0; k < (TS / PARTS); ++k) {
            float2 c = tile[(k << 4) + part];
            float dx = qx - c.x;
            float dy = qy - c.y;
            float d2 = fmaf(dx, dx, dy * dy);
            if (d2 < b[KP1 - 1]) {
                // sorted-insert via med3 clamp: b[s] = clamp(d2, b[s-1], b[s])
                // (each med3 reads OLD b values -> depth-1, 17 issue slots)
#pragma unroll
                for (int s = KP1 - 1; s >= 1; --s)
                    b[s] = __builtin_amdgcn_fmed3f(d2, b[s - 1], b[s]);
                b[0] = fminf(b[0], d2);
            }
        }
    }

#pragma unroll
    for (int i = 0; i < KP1; ++i) mrg[ql][part][i] = b[i];
    __syncthreads();

    if (part == 0 && q < n) {
        // merge the other 15 partitions' sorted lists into b
        for (int pp = 1; pp < PARTS; ++pp) {
#pragma unroll 1
            for (int i = 0; i < KP1; ++i) {
                float d2 = mrg[ql][pp][i];
                if (d2 >= b[KP1 - 1]) break;   // lists ascending; rest can't qualify
#pragma unroll
                for (int s = KP1 - 1; s >= 1; --s)
                    b[s] = __builtin_amdgcn_fmed3f(d2, b[s - 1], b[s]);
                b[0] = fminf(b[0], d2);
            }
        }
        // b[0] == 0 (self); output b[1..16] as distances
        float4* out4 = (float4*)(out + (size_t)q * NK);
#pragma unroll
        for (int i = 0; i < 4; ++i) {
            out4[i] = make_float4(sqrtf(b[4 * i + 1]), sqrtf(b[4 * i + 2]),
                                  sqrtf(b[4 * i + 3]), sqrtf(b[4 * i + 4]));
        }
    }
}

extern "C" void kernel_launch(void* const* d_in, const int* in_sizes, int n_in,
                              void* d_out, int out_size, void* d_ws, size_t ws_size,
                              hipStream_t stream) {
    const float* p = (const float*)d_in[0];
    float* out = (float*)d_out;
    const int n = in_sizes[0] / 3;
    const int grid = (n + BQ - 1) / BQ;
    hipLaunchKernelGGL(knn_kernel, dim3(grid), dim3(BLOCK), 0, stream, p, out, n);
}

// Round 5
// 200.590 us; speedup vs baseline: 2.0008x; 1.2826x over previous
//
#include <hip/hip_runtime.h>
#include <math.h>

// 2D 16-NN distances, N=16384, exact, via uniform-grid binning.
// Pipeline (all on stream, graph-capture safe):
//   memset counts -> bbox -> count -> scan(prefix) -> scatter -> knn_query
// Grid 128x128 over measured bbox, SERPENTINE cell order (odd rows reversed)
// so consecutive sorted points are always spatially adjacent and any cell
// rectangle is a set of contiguous per-row spans in the sorted array.
// Query kernel: block = 16 consecutive sorted queries x 16 partitions;
// candidate rect staged to LDS in chunks; per-lane sorted top-17 (incl. self
// at d2=0, dropped at output == reference idx[:,1:]); ring expansion
// R=1,2,4,... stops when >=17 pts (summed over parts) lie within R*hmin,
// which lower-bounds the distance to any unvisited cell. Exact.

#define G      128
#define NC     (G * G)
#define NK     16
#define KP1    17
#define BQ     16
#define PARTS  16
#define CAP    2048
#define BLOCK  256

// ws layout (bytes); total 393344 B required
#define WS_PARAMS   0
#define WS_COUNTS   64
#define WS_OFFSETS  (WS_COUNTS + NC * 4)                  // 65600
#define WS_CURSOR   131200
#define WS_SXY      196736
#define WS_SIDX     327808

__device__ __forceinline__ int clampi(int v, int lo, int hi) {
    return v < lo ? lo : (v > hi ? hi : v);
}

__device__ __forceinline__ void cell_xy(float x, float y, const float* params,
                                        int& cx, int& cy) {
    cx = clampi((int)((x - params[0]) * params[2]), 0, G - 1);
    cy = clampi((int)((y - params[1]) * params[3]), 0, G - 1);
}

__device__ __forceinline__ int serp_idx(int cx, int cy) {
    int xx = (cy & 1) ? (G - 1 - cx) : cx;
    return cy * G + xx;
}

__global__ __launch_bounds__(1024) void bbox_kernel(const float* __restrict__ p, int n,
                                                    float* __restrict__ params) {
    __shared__ float sm[4][1024];
    const int t = threadIdx.x;
    float mnx = 3e38f, mny = 3e38f, mxx = -3e38f, mxy = -3e38f;
    for (int i = t; i < n; i += 1024) {
        float x = p[3 * i], y = p[3 * i + 1];
        mnx = fminf(mnx, x); mxx = fmaxf(mxx, x);
        mny = fminf(mny, y); mxy = fmaxf(mxy, y);
    }
    sm[0][t] = mnx; sm[1][t] = mny; sm[2][t] = mxx; sm[3][t] = mxy;
    __syncthreads();
    for (int s = 512; s > 0; s >>= 1) {
        if (t < s) {
            sm[0][t] = fminf(sm[0][t], sm[0][t + s]);
            sm[1][t] = fminf(sm[1][t], sm[1][t + s]);
            sm[2][t] = fmaxf(sm[2][t], sm[2][t + s]);
            sm[3][t] = fmaxf(sm[3][t], sm[3][t + s]);
        }
        __syncthreads();
    }
    if (t == 0) {
        float x0 = sm[0][0], y0 = sm[1][0];
        float rx = fmaxf(sm[2][0] - x0, 1e-20f);
        float ry = fmaxf(sm[3][0] - y0, 1e-20f);
        float ihx = (float)G * (1.0f - 1e-5f) / rx;
        float ihy = (float)G * (1.0f - 1e-5f) / ry;
        params[0] = x0; params[1] = y0; params[2] = ihx; params[3] = ihy;
        params[4] = 1.0f / fmaxf(ihx, ihy);   // hmin: true min cell dimension
    }
}

__global__ void count_kernel(const float* __restrict__ p, int n,
                             const float* __restrict__ params, int* __restrict__ counts) {
    int i = blockIdx.x * blockDim.x + threadIdx.x;
    if (i >= n) return;
    int cx, cy;
    cell_xy(p[3 * i], p[3 * i + 1], params, cx, cy);
    atomicAdd(&counts[serp_idx(cx, cy)], 1);
}

__global__ __launch_bounds__(1024) void scan_kernel(const int* __restrict__ counts,
                                                    int* __restrict__ offsets,
                                                    int* __restrict__ cursor) {
    __shared__ int sm[1024];
    const int t = threadIdx.x;
    int c[16];
    int s = 0;
#pragma unroll
    for (int k = 0; k < 16; ++k) { c[k] = counts[t * 16 + k]; s += c[k]; }
    sm[t] = s;
    __syncthreads();
    for (int off = 1; off < 1024; off <<= 1) {
        int v = (t >= off) ? sm[t - off] : 0;
        __syncthreads();
        sm[t] += v;
        __syncthreads();
    }
    int base = sm[t] - s;  // exclusive prefix
#pragma unroll
    for (int k = 0; k < 16; ++k) {
        offsets[t * 16 + k] = base;
        cursor[t * 16 + k] = base;
        base += c[k];
    }
    if (t == 1023) offsets[NC] = base;   // == n
}

__global__ void scatter_kernel(const float* __restrict__ p, int n,
                               const float* __restrict__ params, int* __restrict__ cursor,
                               float2* __restrict__ sxy, int* __restrict__ sidx) {
    int i = blockIdx.x * blockDim.x + threadIdx.x;
    if (i >= n) return;
    float x = p[3 * i], y = p[3 * i + 1];
    int cx, cy;
    cell_xy(x, y, params, cx, cy);
    int pos = atomicAdd(&cursor[serp_idx(cx, cy)], 1);
    sxy[pos] = make_float2(x, y);
    sidx[pos] = i;
}

__global__ __launch_bounds__(BLOCK, 4) void knn_query(const float* __restrict__ params,
                                                      const int* __restrict__ offsets,
                                                      const float2* __restrict__ sxy,
                                                      const int* __restrict__ sidx,
                                                      float* __restrict__ out, int n) {
    __shared__ float2 cand[CAP];
    __shared__ float  mrg[BQ][PARTS][KP1];
    __shared__ int    rect[4];   // cxmin, cxmax, cymin, cymax
    __shared__ int    qcnt[BQ];

    const int t    = threadIdx.x;
    const int ql   = t >> 4;
    const int part = t & 15;
    const int sq   = blockIdx.x * BQ + ql;
    const int sqc  = (sq < n) ? sq : (n - 1);

    const float x0 = params[0], y0 = params[1];
    const float ihx = params[2], ihy = params[3], hmin = params[4];

    const float2 qp = sxy[sqc];
    const float qx = qp.x, qy = qp.y;
    int cx = clampi((int)((qx - x0) * ihx), 0, G - 1);
    int cy = clampi((int)((qy - y0) * ihy), 0, G - 1);

    if (t == 0) { rect[0] = G; rect[1] = -1; rect[2] = G; rect[3] = -1; }
    if (t < BQ) qcnt[t] = 0;
    __syncthreads();
    if (part == 0) {
        atomicMin(&rect[0], cx); atomicMax(&rect[1], cx);
        atomicMin(&rect[2], cy); atomicMax(&rect[3], cy);
    }
    __syncthreads();
    const int cxmin = rect[0], cxmax = rect[1], cymin = rect[2], cymax = rect[3];

    float b[KP1];
#pragma unroll
    for (int i = 0; i < KP1; ++i) b[i] = 3.0e38f;

    int fill = 0;   // block-uniform

    auto scan_buf = [&](int cnt) {
        for (int i = part; i < cnt; i += PARTS) {
            float2 c2 = cand[i];
            float dx = qx - c2.x, dy = qy - c2.y;
            float d2 = fmaf(dx, dx, dy * dy);
            if (d2 < b[KP1 - 1]) {
#pragma unroll
                for (int s = KP1 - 1; s >= 1; --s)
                    b[s] = __builtin_amdgcn_fmed3f(d2, b[s - 1], b[s]);
                b[0] = fminf(b[0], d2);
            }
        }
    };

    // append cells [xlo..xhi] of row ry (serpentine -> contiguous sorted span)
    auto append = [&](int ry, int xlo, int xhi) {
        int lo = (ry & 1) ? (G - 1 - xhi) : xlo;
        int hi = (ry & 1) ? (G - 1 - xlo) : xhi;
        int s = offsets[ry * G + lo];
        int e = offsets[ry * G + hi + 1];
        while (s < e) {
            int m = min(e - s, CAP - fill);
            for (int i = t; i < m; i += BLOCK) cand[fill + i] = sxy[s + i];
            fill += m; s += m;
            if (fill == CAP) {
                __syncthreads();
                scan_buf(CAP);
                __syncthreads();
                fill = 0;
            }
        }
    };

    int pxlo = G, pxhi = -1, pylo = G, pyhi = -1;   // processed rect (empty)
    int R = 1;
    while (true) {
        const int nxlo = max(cxmin - R, 0), nxhi = min(cxmax + R, G - 1);
        const int nylo = max(cymin - R, 0), nyhi = min(cymax + R, G - 1);
        for (int ry = nylo; ry <= nyhi; ++ry) {
            if (ry < pylo || ry > pyhi) {
                append(ry, nxlo, nxhi);                    // new full row
            } else {
                if (nxlo < pxlo) append(ry, nxlo, pxlo - 1);   // left growth
                if (nxhi > pxhi) append(ry, pxhi + 1, nxhi);   // right growth
            }
        }
        pxlo = nxlo; pxhi = nxhi; pylo = nylo; pyhi = nyhi;
        if (fill > 0) { __syncthreads(); scan_buf(fill); __syncthreads(); fill = 0; }

        // stop check: >=17 points (incl. self) within R*hmin, which
        // lower-bounds distance to every unvisited cell (Chebyshev >= R+1).
        float Xr = (float)R * hmin;
        float X = Xr * Xr;
        int c = 0;
#pragma unroll
        for (int i = 0; i < KP1; ++i) c += (b[i] <= X) ? 1 : 0;
        atomicAdd(&qcnt[ql], c);
        __syncthreads();
        bool all = true;
        for (int i = 0; i < BQ; ++i) all = all && (qcnt[i] >= KP1);
        bool whole = (nxlo == 0 && nylo == 0 && nxhi == G - 1 && nyhi == G - 1);
        if (all || whole) break;
        __syncthreads();
        if (t < BQ) qcnt[t] = 0;
        __syncthreads();
        R <<= 1;
    }

#pragma unroll
    for (int i = 0; i < KP1; ++i) mrg[ql][part][i] = b[i];
    __syncthreads();

    if (part == 0 && sq < n) {
        for (int pp = 1; pp < PARTS; ++pp) {
#pragma unroll 1
            for (int i = 0; i < KP1; ++i) {
                float d2 = mrg[ql][pp][i];
                if (d2 >= b[KP1 - 1]) break;   // ascending lists
#pragma unroll
                for (int s = KP1 - 1; s >= 1; --s)
                    b[s] = __builtin_amdgcn_fmed3f(d2, b[s - 1], b[s]);
                b[0] = fminf(b[0], d2);
            }
        }
        // b[0] == 0 (self); write 16 neighbor distances to original row
        float4* op = (float4*)(out + (size_t)sidx[sq] * NK);
#pragma unroll
        for (int i = 0; i < 4; ++i)
            op[i] = make_float4(sqrtf(b[4 * i + 1]), sqrtf(b[4 * i + 2]),
                                sqrtf(b[4 * i + 3]), sqrtf(b[4 * i + 4]));
    }
}

extern "C" void kernel_launch(void* const* d_in, const int* in_sizes, int n_in,
                              void* d_out, int out_size, void* d_ws, size_t ws_size,
                              hipStream_t stream) {
    const float* p = (const float*)d_in[0];
    float* out = (float*)d_out;
    const int n = in_sizes[0] / 3;

    char* ws = (char*)d_ws;
    float* params  = (float*)(ws + WS_PARAMS);
    int*   counts  = (int*)(ws + WS_COUNTS);
    int*   offsets = (int*)(ws + WS_OFFSETS);
    int*   cursor  = (int*)(ws + WS_CURSOR);
    float2* sxy    = (float2*)(ws + WS_SXY);
    int*   sidx    = (int*)(ws + WS_SIDX);

    hipMemsetAsync(counts, 0, NC * sizeof(int), stream);
    hipLaunchKernelGGL(bbox_kernel, dim3(1), dim3(1024), 0, stream, p, n, params);
    const int nb = (n + 255) / 256;
    hipLaunchKernelGGL(count_kernel, dim3(nb), dim3(256), 0, stream, p, n, params, counts);
    hipLaunchKernelGGL(scan_kernel, dim3(1), dim3(1024), 0, stream, counts, offsets, cursor);
    hipLaunchKernelGGL(scatter_kernel, dim3(nb), dim3(256), 0, stream, p, n, params, cursor, sxy, sidx);
    const int qb = (n + BQ - 1) / BQ;
    hipLaunchKernelGGL(knn_query, dim3(qb), dim3(BLOCK), 0, stream,
                       params, offsets, sxy, sidx, out, n);
}